// Round 8
// baseline (375.437 us; speedup 1.0000x reference)
//
#include <hip/hip_runtime.h>
#include <cfloat>
#include <cstdint>

#define BATCH 2
#define NSEQ 2048
#define CIN 512
#define HEADS 8
#define DIM 64
#define HD 512
#define QKV3 1536

typedef short short8 __attribute__((ext_vector_type(8)));
typedef float f32x4 __attribute__((ext_vector_type(4)));
typedef unsigned short ushort_t;

__device__ __forceinline__ unsigned short f2bf(float f) {
    return (unsigned short)(__float_as_uint(f) >> 16);
}
__device__ __forceinline__ float bf2f(unsigned short h) {
    return __uint_as_float(((unsigned int)h) << 16);
}

// ---------- split + transpose BOTH weights in one launch ------------------
// grid (32, 8): bx<24 -> w_qkv [512][1536]; bx>=24 -> w_out [512][512]
__global__ __launch_bounds__(256) void split_wT_kernel(
    const float* __restrict__ Wq, const float* __restrict__ Wo,
    ushort_t* __restrict__ WqTh, ushort_t* __restrict__ WqTl,
    ushort_t* __restrict__ WoTh, ushort_t* __restrict__ WoTl)
{
    __shared__ float T[64][65];
    const int bx = blockIdx.x;
    const float* W; ushort_t *WTh, *WTl; int N, n0;
    if (bx < 24) { W = Wq; WTh = WqTh; WTl = WqTl; N = QKV3; n0 = bx * 64; }
    else         { W = Wo; WTh = WoTh; WTl = WoTl; N = HD;   n0 = (bx - 24) * 64; }
    const int K = CIN;
    const int k0 = blockIdx.y * 64;
    const int tid = threadIdx.x;
    #pragma unroll
    for (int i = 0; i < 4; ++i) {
        int c = tid + i * 256;
        int row = c >> 4, c4 = c & 15;
        *(float4*)&T[row][c4*4] = *(const float4*)(W + (size_t)(k0 + row) * N + n0 + c4*4);
    }
    __syncthreads();
    const int n = tid >> 2, kseg = tid & 3;
    short8 hh0, ll0, hh1, ll1;
    #pragma unroll
    for (int e = 0; e < 8; ++e) {
        float x0 = T[kseg*16 + e][n];
        unsigned short h0 = f2bf(x0);
        hh0[e] = (short)h0; ll0[e] = (short)f2bf(x0 - bf2f(h0));
        float x1 = T[kseg*16 + 8 + e][n];
        unsigned short h1 = f2bf(x1);
        hh1[e] = (short)h1; ll1[e] = (short)f2bf(x1 - bf2f(h1));
    }
    size_t o = (size_t)(n0 + n) * K + k0 + kseg * 16;
    *(short8*)(WTh + o)     = hh0;
    *(short8*)(WTh + o + 8) = hh1;
    *(short8*)(WTl + o)     = ll0;
    *(short8*)(WTl + o + 8) = ll1;
}

// ---------- split-bf16 MFMA GEMM: C[M][N] = A[M][K](f32) @ BT[N][K](bf16 h/l) --
__global__ __launch_bounds__(256, 2) void gemm_split_kernel(
    const float* __restrict__ A, const ushort_t* __restrict__ BTh,
    const ushort_t* __restrict__ BTl, float* __restrict__ C,
    int M, int N, int K)
{
    __shared__ ushort_t Ash[128][72], Asl[128][72];
    __shared__ ushort_t Bsh[64][72],  Bsl[64][72];
    const int bm = blockIdx.y * 128, bn = blockIdx.x * 64;
    const int tid = threadIdx.x;
    const int wave = tid >> 6, lane = tid & 63;
    const int lg = lane >> 4, lm = lane & 15;
    const int wm = wave >> 1, wn = wave & 1;
    const int arow = tid >> 3, aseg = tid & 7;

    f32x4 acc[4][2];
    #pragma unroll
    for (int mf = 0; mf < 4; ++mf)
        #pragma unroll
        for (int nf = 0; nf < 2; ++nf) acc[mf][nf] = (f32x4){0.f,0.f,0.f,0.f};

    float4 ar[8];
    uint4 brh[2], brl[2];
    const int nkt = K >> 6;

    #define G_ISSUE(K0)                                                          \
        { _Pragma("unroll")                                                      \
          for (int i = 0; i < 4; ++i) {                                          \
            const float* ap = A + (size_t)(bm + arow + 32*i) * K + (K0) + aseg*8;\
            ar[2*i]   = *(const float4*)ap;                                      \
            ar[2*i+1] = *(const float4*)(ap + 4);                                \
          }                                                                      \
          _Pragma("unroll")                                                      \
          for (int i = 0; i < 2; ++i) {                                          \
            size_t bo = (size_t)(bn + arow + 32*i) * K + (K0) + aseg*8;          \
            brh[i] = *(const uint4*)(BTh + bo);                                  \
            brl[i] = *(const uint4*)(BTl + bo);                                  \
          } }

    G_ISSUE(0)
    for (int kt = 0; kt < nkt; ++kt) {
        __syncthreads();
        #pragma unroll
        for (int i = 0; i < 4; ++i) {
            float av[8];
            *(float4*)&av[0] = ar[2*i];
            *(float4*)&av[4] = ar[2*i+1];
            short8 hh, ll;
            #pragma unroll
            for (int e = 0; e < 8; ++e) {
                unsigned short hi = f2bf(av[e]);
                hh[e] = (short)hi;
                ll[e] = (short)f2bf(av[e] - bf2f(hi));
            }
            *(short8*)&Ash[arow + 32*i][aseg*8] = hh;
            *(short8*)&Asl[arow + 32*i][aseg*8] = ll;
        }
        #pragma unroll
        for (int i = 0; i < 2; ++i) {
            *(uint4*)&Bsh[arow + 32*i][aseg*8] = brh[i];
            *(uint4*)&Bsl[arow + 32*i][aseg*8] = brl[i];
        }
        if (kt + 1 < nkt) G_ISSUE((kt + 1) * 64)
        __syncthreads();
        #pragma unroll
        for (int ks = 0; ks < 2; ++ks) {
            short8 afh[4], afl[4], bfh[2], bfl[2];
            #pragma unroll
            for (int mf = 0; mf < 4; ++mf) {
                afh[mf] = *(const short8*)&Ash[wm*64 + mf*16 + lm][ks*32 + lg*8];
                afl[mf] = *(const short8*)&Asl[wm*64 + mf*16 + lm][ks*32 + lg*8];
            }
            #pragma unroll
            for (int nf = 0; nf < 2; ++nf) {
                bfh[nf] = *(const short8*)&Bsh[wn*32 + nf*16 + lm][ks*32 + lg*8];
                bfl[nf] = *(const short8*)&Bsl[wn*32 + nf*16 + lm][ks*32 + lg*8];
            }
            #pragma unroll
            for (int mf = 0; mf < 4; ++mf)
                #pragma unroll
                for (int nf = 0; nf < 2; ++nf) {
                    acc[mf][nf] = __builtin_amdgcn_mfma_f32_16x16x32_bf16(afh[mf], bfh[nf], acc[mf][nf], 0, 0, 0);
                    acc[mf][nf] = __builtin_amdgcn_mfma_f32_16x16x32_bf16(afh[mf], bfl[nf], acc[mf][nf], 0, 0, 0);
                    acc[mf][nf] = __builtin_amdgcn_mfma_f32_16x16x32_bf16(afl[mf], bfh[nf], acc[mf][nf], 0, 0, 0);
                }
        }
    }
    #pragma unroll
    for (int mf = 0; mf < 4; ++mf)
        #pragma unroll
        for (int nf = 0; nf < 2; ++nf)
            #pragma unroll
            for (int r = 0; r < 4; ++r)
                C[(size_t)(bm + wm*64 + mf*16 + lg*4 + r) * N + bn + wn*32 + nf*16 + lm]
                    = acc[mf][nf][r];
    #undef G_ISSUE
}

// ------- fused qkv prep: l2norm+split Q,K  and  transposed/permuted V ----
__global__ __launch_bounds__(256) void qkv_prep_kernel(
    const float* __restrict__ qkv,
    ushort_t* __restrict__ Qh, ushort_t* __restrict__ Ql,
    ushort_t* __restrict__ Kh, ushort_t* __restrict__ Kl,
    ushort_t* __restrict__ Vth, ushort_t* __restrict__ Vtl)
{
    __shared__ float Vf[64][65];
    const int id = blockIdx.x;
    const int bh = id >> 5, nt = id & 31;
    const int b = bh >> 3, h = bh & 7;
    const int n0 = nt * 64;
    const int tid = threadIdx.x;
    {
        const int row = tid >> 2, dseg = tid & 3;
        const float* src = qkv + ((size_t)(b * NSEQ + n0 + row)) * QKV3
                         + h * 192 + dseg * 48;
        float f[48];
        #pragma unroll
        for (int i = 0; i < 12; ++i)
            *(float4*)&f[i*4] = *(const float4*)(src + i*4);
        float nq = 0.f, nk = 0.f;
        #pragma unroll
        for (int e = 0; e < 16; ++e) {
            nq = fmaf(f[3*e], f[3*e], nq);
            nk = fmaf(f[3*e+1], f[3*e+1], nk);
        }
        nq += __shfl_xor(nq, 1); nq += __shfl_xor(nq, 2);
        nk += __shfl_xor(nk, 1); nk += __shfl_xor(nk, 2);
        float rq = 1.f / fmaxf(sqrtf(nq), 1e-12f);
        float rk = 1.f / fmaxf(sqrtf(nk), 1e-12f);
        short8 qh8[2], ql8[2], kh8[2], kl8[2];
        #pragma unroll
        for (int e = 0; e < 16; ++e) {
            float q = f[3*e] * rq, k = f[3*e+1] * rk;
            unsigned short qhi = f2bf(q), khi = f2bf(k);
            qh8[e>>3][e&7] = (short)qhi;
            ql8[e>>3][e&7] = (short)f2bf(q - bf2f(qhi));
            kh8[e>>3][e&7] = (short)khi;
            kl8[e>>3][e&7] = (short)f2bf(k - bf2f(khi));
            Vf[dseg*16 + e][row] = f[3*e+2];
        }
        size_t o = ((size_t)bh * NSEQ + n0 + row) * DIM + dseg * 16;
        *(short8*)(Qh + o) = qh8[0]; *(short8*)(Qh + o + 8) = qh8[1];
        *(short8*)(Ql + o) = ql8[0]; *(short8*)(Ql + o + 8) = ql8[1];
        *(short8*)(Kh + o) = kh8[0]; *(short8*)(Kh + o + 8) = kh8[1];
        *(short8*)(Kl + o) = kl8[0]; *(short8*)(Kl + o + 8) = kl8[1];
    }
    __syncthreads();
    {   // Vt[bh][d][n] with the PV fragment j-permutation (within 32-blocks)
        const int d = tid >> 2, seg = tid & 3;
        ushort_t th[16], tl[16];
        #pragma unroll
        for (int t = 0; t < 16; ++t) {
            int p = seg * 16 + t;
            int s = (p & 35) | ((p & 4) << 2) | ((p >> 1) & 12);
            float v = Vf[d][s];
            unsigned short hi = f2bf(v);
            th[t] = hi;
            tl[t] = f2bf(v - bf2f(hi));
        }
        size_t o = ((size_t)bh * DIM + d) * NSEQ + n0 + seg * 16;
        *(uint4*)(Vth + o)     = *(uint4*)&th[0];
        *(uint4*)(Vth + o + 8) = *(uint4*)&th[8];
        *(uint4*)(Vtl + o)     = *(uint4*)&tl[0];
        *(uint4*)(Vtl + o + 8) = *(uint4*)&tl[8];
    }
}

// ---------------- MFMA flash attention v7: runtime j-split ---------------
// Q-tile 128 (4 waves x 32 rows), KVBLK=32 dbuf, grid 256*ns
__global__ __launch_bounds__(256, 4) void attn_mfma_kernel(
    const ushort_t* __restrict__ Qh, const ushort_t* __restrict__ Ql,
    const ushort_t* __restrict__ Kh, const ushort_t* __restrict__ Kl,
    const ushort_t* __restrict__ Vth, const ushort_t* __restrict__ Vtl,
    const float* __restrict__ bias, const float* __restrict__ temp_p,
    const uint8_t* __restrict__ mask,
    float* __restrict__ Opart, float* __restrict__ Ml,
    int ns, int base, int rem)
{
    __shared__ ushort_t KsH[2][32][72], KsL[2][32][72];   // [buf][j][d]
    __shared__ ushort_t VsH[2][64][36], VsL[2][64][36];   // [buf][d][j-perm]

    const int id = blockIdx.x;
    const int h = id & 7;                  // XCD-grouped
    const int rest = id >> 3;              // 0 .. 2*16*ns-1
    const int per_b = 16 * ns;
    const int b = rest / per_b;
    const int r2 = rest - b * per_b;
    const int js = r2 >> 4;                // 0..ns-1
    const int qt = r2 & 15;
    const int bh = b * 8 + h;
    const int i0 = qt * 128;
    const int tid = threadIdx.x;
    const int wave = tid >> 6, lane = tid & 63;
    const int lg = lane >> 4, lm = lane & 15;
    const int qbase = i0 + wave * 32;
    const float temp = *temp_p;
    const int krow = tid >> 3, kseg = tid & 7;   // K staging: 32 x 8
    const int vrow = tid >> 2, vseg = tid & 3;   // V staging: 64 x 4

    short8 qfh[2][2], qfl[2][2];
    #pragma unroll
    for (int m = 0; m < 2; ++m) {
        size_t qo = ((size_t)(bh * NSEQ + qbase + 16*m + lm)) * DIM + lg * 8;
        qfh[m][0] = *(const short8*)(Qh + qo);
        qfh[m][1] = *(const short8*)(Qh + qo + 32);
        qfl[m][0] = *(const short8*)(Ql + qo);
        qfl[m][1] = *(const short8*)(Ql + qo + 32);
    }
    bool rowm[2];
    rowm[0] = mask[(size_t)b * NSEQ + qbase + lm] != 0;
    rowm[1] = mask[(size_t)b * NSEQ + qbase + 16 + lm] != 0;

    float m_r[2] = {-FLT_MAX, -FLT_MAX};
    float l_r[2] = {0.f, 0.f};
    f32x4 oa[2][4];
    #pragma unroll
    for (int m = 0; m < 2; ++m)
        #pragma unroll
        for (int dt = 0; dt < 4; ++dt) oa[m][dt] = (f32x4){0.f,0.f,0.f,0.f};

    const int NT = base + (js < rem ? 1 : 0);
    const int tstart = js * base + (js < rem ? js : rem);
    const int jbase = tstart * 32;
    uint4 skh, skl, svh, svl;

    #define A_ISSUE(J0) {                                                      \
        size_t gk = ((size_t)(bh * NSEQ) + (J0) + krow) * DIM + kseg*8;        \
        size_t gv = ((size_t)(bh * DIM) + vrow) * NSEQ + (J0) + vseg*8;        \
        skh = *(const uint4*)(Kh  + gk);                                       \
        skl = *(const uint4*)(Kl  + gk);                                       \
        svh = *(const uint4*)(Vth + gv);                                       \
        svl = *(const uint4*)(Vtl + gv); }
    #define STAGE(BUF) {                                                       \
        *(uint4*)&KsH[BUF][krow][kseg*8] = skh;                                \
        *(uint4*)&KsL[BUF][krow][kseg*8] = skl;                                \
        *(uint4*)&VsH[BUF][vrow][vseg*8] = svh;                                \
        *(uint4*)&VsL[BUF][vrow][vseg*8] = svl; }

    A_ISSUE(jbase)
    STAGE(0)
    A_ISSUE(jbase + 32)
    float4 bb[2][2];
    #pragma unroll
    for (int m = 0; m < 2; ++m)
        #pragma unroll
        for (int jt = 0; jt < 2; ++jt)
            bb[m][jt] = *(const float4*)(bias
                + ((size_t)h * NSEQ + qbase + 16*m + lm) * NSEQ
                + jbase + jt*16 + lg*4);
    uint8_t mk = mask[(size_t)b * NSEQ + jbase + (lane & 31)];
    __syncthreads();

    #pragma unroll 2
    for (int t = 0; t < NT; ++t) {
        const int cur = t & 1;
        const int j0 = jbase + t * 32;

        // ---- prefetch next tile's bias/mask; stage t+1; issue t+2 ----
        float4 bbn[2][2];
        uint8_t mkn = 0;
        if (t + 1 < NT) {
            #pragma unroll
            for (int m = 0; m < 2; ++m)
                #pragma unroll
                for (int jt = 0; jt < 2; ++jt)
                    bbn[m][jt] = *(const float4*)(bias
                        + ((size_t)h * NSEQ + qbase + 16*m + lm) * NSEQ
                        + j0 + 32 + jt*16 + lg*4);
            mkn = mask[(size_t)b * NSEQ + j0 + 32 + (lane & 31)];
            STAGE(cur ^ 1)
            if (t + 2 < NT) A_ISSUE(j0 + 64)
        }
        unsigned long long bal = __ballot(mk != 0);   // low 32 bits = tile cols

        // ---- S^T = K.Q (swapped), split MFMA ----
        f32x4 sac[2][2];
        #pragma unroll
        for (int m = 0; m < 2; ++m)
            #pragma unroll
            for (int jt = 0; jt < 2; ++jt) sac[m][jt] = (f32x4){0.f,0.f,0.f,0.f};
        __builtin_amdgcn_s_setprio(1);
        #pragma unroll
        for (int jt = 0; jt < 2; ++jt)
            #pragma unroll
            for (int ks = 0; ks < 2; ++ks) {
                short8 kbh = *(const short8*)(&KsH[cur][jt*16 + lm][ks*32 + lg*8]);
                short8 kbl = *(const short8*)(&KsL[cur][jt*16 + lm][ks*32 + lg*8]);
                #pragma unroll
                for (int m = 0; m < 2; ++m) {
                    sac[m][jt] = __builtin_amdgcn_mfma_f32_16x16x32_bf16(kbh, qfh[m][ks], sac[m][jt], 0, 0, 0);
                    sac[m][jt] = __builtin_amdgcn_mfma_f32_16x16x32_bf16(kbh, qfl[m][ks], sac[m][jt], 0, 0, 0);
                    sac[m][jt] = __builtin_amdgcn_mfma_f32_16x16x32_bf16(kbl, qfh[m][ks], sac[m][jt], 0, 0, 0);
                }
            }
        __builtin_amdgcn_s_setprio(0);

        // ---- in-register online softmax with defer-max ----
        short8 pah[2], pal[2];
        #pragma unroll
        for (int m = 0; m < 2; ++m) {
            float sv[2][4];
            #pragma unroll
            for (int jt = 0; jt < 2; ++jt) {
                unsigned int nib = (unsigned int)(bal >> (jt*16 + lg*4)) & 0xFu;
                #pragma unroll
                for (int r = 0; r < 4; ++r) {
                    bool dead = rowm[m] || ((nib >> r) & 1u);
                    float bv = (r == 0) ? bb[m][jt].x : (r == 1) ? bb[m][jt].y
                             : (r == 2) ? bb[m][jt].z : bb[m][jt].w;
                    sv[jt][r] = dead ? -FLT_MAX : fmaf(sac[m][jt][r], temp, bv);
                }
            }
            float pmax = fmaxf(fmaxf(fmaxf(sv[0][0], sv[0][1]), fmaxf(sv[0][2], sv[0][3])),
                               fmaxf(fmaxf(sv[1][0], sv[1][1]), fmaxf(sv[1][2], sv[1][3])));
            pmax = fmaxf(pmax, __shfl_xor(pmax, 16));
            pmax = fmaxf(pmax, __shfl_xor(pmax, 32));
            if (!__all(pmax <= m_r[m] + 8.f)) {      // rare rescale
                float mn = fmaxf(m_r[m], pmax);
                float sc = __expf(m_r[m] - mn);
                m_r[m] = mn;
                l_r[m] *= sc;
                #pragma unroll
                for (int r = 0; r < 4; ++r) {
                    float sq = __shfl(sc, lg*4 + r);
                    #pragma unroll
                    for (int dt = 0; dt < 4; ++dt) oa[m][dt][r] *= sq;
                }
            }
            float rs = 0.f;
            #pragma unroll
            for (int jt = 0; jt < 2; ++jt)
                #pragma unroll
                for (int r = 0; r < 4; ++r) {
                    float pf = __expf(sv[jt][r] - m_r[m]);
                    rs += pf;
                    unsigned short hi = f2bf(pf);
                    pah[m][jt*4 + r] = (short)hi;
                    pal[m][jt*4 + r] = (short)f2bf(pf - bf2f(hi));
                }
            rs += __shfl_xor(rs, 16);
            rs += __shfl_xor(rs, 32);
            l_r[m] += rs;
        }

        // ---- O += P.V ----
        __builtin_amdgcn_s_setprio(1);
        #pragma unroll
        for (int dt = 0; dt < 4; ++dt) {
            short8 vbh = *(const short8*)(&VsH[cur][dt*16 + lm][lg*8]);
            short8 vbl = *(const short8*)(&VsL[cur][dt*16 + lm][lg*8]);
            #pragma unroll
            for (int m = 0; m < 2; ++m) {
                oa[m][dt] = __builtin_amdgcn_mfma_f32_16x16x32_bf16(pah[m], vbh, oa[m][dt], 0, 0, 0);
                oa[m][dt] = __builtin_amdgcn_mfma_f32_16x16x32_bf16(pah[m], vbl, oa[m][dt], 0, 0, 0);
                oa[m][dt] = __builtin_amdgcn_mfma_f32_16x16x32_bf16(pal[m], vbh, oa[m][dt], 0, 0, 0);
            }
        }
        __builtin_amdgcn_s_setprio(0);
        __syncthreads();
        #pragma unroll
        for (int m = 0; m < 2; ++m)
            #pragma unroll
            for (int jt = 0; jt < 2; ++jt) bb[m][jt] = bbn[m][jt];
        mk = mkn;
    }
    #undef A_ISSUE
    #undef STAGE

    // ---- epilogue: f32 partials + (m,l) ----
    #pragma unroll
    for (int m = 0; m < 2; ++m)
        #pragma unroll
        for (int dt = 0; dt < 4; ++dt)
            #pragma unroll
            for (int r = 0; r < 4; ++r)
                Opart[((size_t)(js*16 + bh) * NSEQ + qbase + 16*m + lg*4 + r) * 64
                      + dt*16 + lm] = oa[m][dt][r];
    if (lane < 16) {
        #pragma unroll
        for (int m = 0; m < 2; ++m) {
            size_t mi = ((size_t)(js*16 + bh) * NSEQ + qbase + 16*m + lm) * 2;
            Ml[mi]     = m_r[m];
            Ml[mi + 1] = l_r[m];
        }
    }
}

// ------- merge ns j-split partials -> AO f32 [M][HD] ---------------------
__global__ __launch_bounds__(256) void merge_kernel(
    const float* __restrict__ Opart, const float* __restrict__ Ml,
    float* __restrict__ AO, int ns)
{
    int row = blockIdx.x * 4 + (threadIdx.x >> 6);
    int d = threadIdx.x & 63;
    int bh = row >> 11, n = row & (NSEQ - 1);
    int bq = bh >> 3, hq = bh & 7;
    float mv[4], lv[4];
    float mm = -FLT_MAX;
    for (int p = 0; p < ns; ++p) {
        size_t mi = ((size_t)(p*16 + bh) * NSEQ + n) * 2;
        mv[p] = Ml[mi]; lv[p] = Ml[mi + 1];
        mm = fmaxf(mm, mv[p]);
    }
    float l = 0.f, o = 0.f;
    for (int p = 0; p < ns; ++p) {
        float w = __expf(mv[p] - mm);
        l += lv[p] * w;
        o += Opart[((size_t)(p*16 + bh) * NSEQ + n) * 64 + d] * w;
    }
    o /= l;
    AO[((size_t)(bq * NSEQ + n)) * HD + hq * DIM + d] = o;
}

extern "C" void kernel_launch(void* const* d_in, const int* in_sizes, int n_in,
                              void* d_out, int out_size, void* d_ws, size_t ws_size,
                              hipStream_t stream)
{
    const float*   x        = (const float*)d_in[0];
    const float*   w_qkv    = (const float*)d_in[1];
    const float*   w_out    = (const float*)d_in[2];
    const float*   pos_bias = (const float*)d_in[3];
    const float*   temp     = (const float*)d_in[4];
    const uint8_t* mask     = (const uint8_t*)d_in[5];
    float* out = (float*)d_out;

    const int M = BATCH * NSEQ;                        // 4096
    const size_t NE = (size_t)BATCH * HEADS * NSEQ * DIM;
    const size_t QKVB   = (size_t)M * QKV3 * 4;        // qkv_lin bytes (25.2 MB)
    const size_t PART1  = (size_t)16 * NSEQ * 64 * 4;  // per-split partial bytes (8.4 MB)
    const size_t WB     = (size_t)(QKV3 + HD) * CIN * 2 * 2;  // weight h+l bytes
    const size_t REG2   = NE * 2 * 6;                  // Q/K/Vt h+l (25.2 MB)

    // choose j-split from available workspace (deterministic: ws_size fixed)
    int ns = 4;
    {
        size_t reg0 = QKVB > (size_t)ns * PART1 ? QKVB : (size_t)ns * PART1;
        size_t mlb  = (size_t)ns * 16 * NSEQ * 2 * 4;
        if (reg0 + WB + mlb + REG2 > ws_size) ns = 3;
    }
    const int base = 64 / ns, rem = 64 % ns;

    char* ws = (char*)d_ws;
    size_t reg0 = QKVB > (size_t)ns * PART1 ? QKVB : (size_t)ns * PART1;
    float* qkv_lin = (float*)ws;
    float* OpartP  = (float*)ws;                 // aliases qkv_lin (dead by then)
    size_t off = reg0;
    ushort_t* WqkvTh = (ushort_t*)(ws + off); off += (size_t)QKV3 * CIN * 2;
    ushort_t* WqkvTl = (ushort_t*)(ws + off); off += (size_t)QKV3 * CIN * 2;
    ushort_t* WoutTh = (ushort_t*)(ws + off); off += (size_t)HD * CIN * 2;
    ushort_t* WoutTl = (ushort_t*)(ws + off); off += (size_t)HD * CIN * 2;
    float*    MlP    = (float*)(ws + off);    off += (size_t)ns * 16 * NSEQ * 2 * 4;
    char* reg2 = ws + off;
    ushort_t* Qh  = (ushort_t*)reg2;
    ushort_t* Ql  = Qh + NE;
    ushort_t* Kh  = Ql + NE;
    ushort_t* Kl  = Kh + NE;
    ushort_t* Vth = Kl + NE;
    ushort_t* Vtl = Vth + NE;
    float* AO = (float*)reg2;       // 8 MB = Qh+Ql slots (dead after attn)

    // 1. both weight splits in one launch
    split_wT_kernel<<<dim3(32, CIN/64), 256, 0, stream>>>(
        w_qkv, w_out, WqkvTh, WqkvTl, WoutTh, WoutTl);
    // 2. qkv projection
    gemm_split_kernel<<<dim3(QKV3/64, M/128), 256, 0, stream>>>(
        x, WqkvTh, WqkvTl, qkv_lin, M, QKV3, CIN);
    // 3. fused l2norm/split + V transpose
    qkv_prep_kernel<<<dim3(BATCH * HEADS * (NSEQ/64)), 256, 0, stream>>>(
        qkv_lin, Qh, Ql, Kh, Kl, Vth, Vtl);
    // 4. attention (j-split ns; Opart overwrites qkv_lin)
    attn_mfma_kernel<<<dim3(256 * ns), 256, 0, stream>>>(
        Qh, Ql, Kh, Kl, Vth, Vtl, pos_bias, temp, mask, OpartP, MlP,
        ns, base, rem);
    // 5. merge partials -> AO f32 (overwrites Qh/Ql)
    merge_kernel<<<dim3(M * HEADS / 4), 256, 0, stream>>>(OpartP, MlP, AO, ns);
    // 6. out projection
    gemm_split_kernel<<<dim3(HD/64, M/128), 256, 0, stream>>>(
        AO, WoutTh, WoutTl, out, M, HD, CIN);
}

// Round 9
// 197.459 us; speedup vs baseline: 1.9013x; 1.9013x over previous
//
#include <hip/hip_runtime.h>
#include <cfloat>
#include <cstdint>

#define BATCH 2
#define NSEQ 2048
#define CIN 512
#define HEADS 8
#define DIM 64
#define HD 512
#define QKV3 1536

typedef short short8 __attribute__((ext_vector_type(8)));
typedef float f32x4 __attribute__((ext_vector_type(4)));
typedef unsigned short ushort_t;

__device__ __forceinline__ unsigned short f2bf(float f) {
    return (unsigned short)(__float_as_uint(f) >> 16);
}
__device__ __forceinline__ float bf2f(unsigned short h) {
    return __uint_as_float(((unsigned int)h) << 16);
}

// ---------- split + transpose BOTH weights in one launch ------------------
// grid (32, 8): bx<24 -> w_qkv [512][1536]; bx>=24 -> w_out [512][512]
__global__ __launch_bounds__(256) void split_wT_kernel(
    const float* __restrict__ Wq, const float* __restrict__ Wo,
    ushort_t* __restrict__ WqTh, ushort_t* __restrict__ WqTl,
    ushort_t* __restrict__ WoTh, ushort_t* __restrict__ WoTl)
{
    __shared__ float T[64][65];
    const int bx = blockIdx.x;
    const float* W; ushort_t *WTh, *WTl; int N, n0;
    if (bx < 24) { W = Wq; WTh = WqTh; WTl = WqTl; N = QKV3; n0 = bx * 64; }
    else         { W = Wo; WTh = WoTh; WTl = WoTl; N = HD;   n0 = (bx - 24) * 64; }
    const int K = CIN;
    const int k0 = blockIdx.y * 64;
    const int tid = threadIdx.x;
    #pragma unroll
    for (int i = 0; i < 4; ++i) {
        int c = tid + i * 256;
        int row = c >> 4, c4 = c & 15;
        *(float4*)&T[row][c4*4] = *(const float4*)(W + (size_t)(k0 + row) * N + n0 + c4*4);
    }
    __syncthreads();
    const int n = tid >> 2, kseg = tid & 3;
    short8 hh0, ll0, hh1, ll1;
    #pragma unroll
    for (int e = 0; e < 8; ++e) {
        float x0 = T[kseg*16 + e][n];
        unsigned short h0 = f2bf(x0);
        hh0[e] = (short)h0; ll0[e] = (short)f2bf(x0 - bf2f(h0));
        float x1 = T[kseg*16 + 8 + e][n];
        unsigned short h1 = f2bf(x1);
        hh1[e] = (short)h1; ll1[e] = (short)f2bf(x1 - bf2f(h1));
    }
    size_t o = (size_t)(n0 + n) * K + k0 + kseg * 16;
    *(short8*)(WTh + o)     = hh0;
    *(short8*)(WTh + o + 8) = hh1;
    *(short8*)(WTl + o)     = ll0;
    *(short8*)(WTl + o + 8) = ll1;
}

// ---------- split-bf16 MFMA GEMM: C[M][N] = A[M][K](f32) @ BT[N][K](bf16 h/l) --
__global__ __launch_bounds__(256, 2) void gemm_split_kernel(
    const float* __restrict__ A, const ushort_t* __restrict__ BTh,
    const ushort_t* __restrict__ BTl, float* __restrict__ C,
    int M, int N, int K)
{
    __shared__ ushort_t Ash[128][72], Asl[128][72];
    __shared__ ushort_t Bsh[64][72],  Bsl[64][72];
    const int bm = blockIdx.y * 128, bn = blockIdx.x * 64;
    const int tid = threadIdx.x;
    const int wave = tid >> 6, lane = tid & 63;
    const int lg = lane >> 4, lm = lane & 15;
    const int wm = wave >> 1, wn = wave & 1;
    const int arow = tid >> 3, aseg = tid & 7;

    f32x4 acc[4][2];
    #pragma unroll
    for (int mf = 0; mf < 4; ++mf)
        #pragma unroll
        for (int nf = 0; nf < 2; ++nf) acc[mf][nf] = (f32x4){0.f,0.f,0.f,0.f};

    float4 ar[8];
    uint4 brh[2], brl[2];
    const int nkt = K >> 6;

    #define G_ISSUE(K0)                                                          \
        { _Pragma("unroll")                                                      \
          for (int i = 0; i < 4; ++i) {                                          \
            const float* ap = A + (size_t)(bm + arow + 32*i) * K + (K0) + aseg*8;\
            ar[2*i]   = *(const float4*)ap;                                      \
            ar[2*i+1] = *(const float4*)(ap + 4);                                \
          }                                                                      \
          _Pragma("unroll")                                                      \
          for (int i = 0; i < 2; ++i) {                                          \
            size_t bo = (size_t)(bn + arow + 32*i) * K + (K0) + aseg*8;          \
            brh[i] = *(const uint4*)(BTh + bo);                                  \
            brl[i] = *(const uint4*)(BTl + bo);                                  \
          } }

    G_ISSUE(0)
    for (int kt = 0; kt < nkt; ++kt) {
        __syncthreads();
        #pragma unroll
        for (int i = 0; i < 4; ++i) {
            float av[8];
            *(float4*)&av[0] = ar[2*i];
            *(float4*)&av[4] = ar[2*i+1];
            short8 hh, ll;
            #pragma unroll
            for (int e = 0; e < 8; ++e) {
                unsigned short hi = f2bf(av[e]);
                hh[e] = (short)hi;
                ll[e] = (short)f2bf(av[e] - bf2f(hi));
            }
            *(short8*)&Ash[arow + 32*i][aseg*8] = hh;
            *(short8*)&Asl[arow + 32*i][aseg*8] = ll;
        }
        #pragma unroll
        for (int i = 0; i < 2; ++i) {
            *(uint4*)&Bsh[arow + 32*i][aseg*8] = brh[i];
            *(uint4*)&Bsl[arow + 32*i][aseg*8] = brl[i];
        }
        if (kt + 1 < nkt) G_ISSUE((kt + 1) * 64)
        __syncthreads();
        #pragma unroll
        for (int ks = 0; ks < 2; ++ks) {
            short8 afh[4], afl[4], bfh[2], bfl[2];
            #pragma unroll
            for (int mf = 0; mf < 4; ++mf) {
                afh[mf] = *(const short8*)&Ash[wm*64 + mf*16 + lm][ks*32 + lg*8];
                afl[mf] = *(const short8*)&Asl[wm*64 + mf*16 + lm][ks*32 + lg*8];
            }
            #pragma unroll
            for (int nf = 0; nf < 2; ++nf) {
                bfh[nf] = *(const short8*)&Bsh[wn*32 + nf*16 + lm][ks*32 + lg*8];
                bfl[nf] = *(const short8*)&Bsl[wn*32 + nf*16 + lm][ks*32 + lg*8];
            }
            #pragma unroll
            for (int mf = 0; mf < 4; ++mf)
                #pragma unroll
                for (int nf = 0; nf < 2; ++nf) {
                    acc[mf][nf] = __builtin_amdgcn_mfma_f32_16x16x32_bf16(afh[mf], bfh[nf], acc[mf][nf], 0, 0, 0);
                    acc[mf][nf] = __builtin_amdgcn_mfma_f32_16x16x32_bf16(afh[mf], bfl[nf], acc[mf][nf], 0, 0, 0);
                    acc[mf][nf] = __builtin_amdgcn_mfma_f32_16x16x32_bf16(afl[mf], bfh[nf], acc[mf][nf], 0, 0, 0);
                }
        }
    }
    #pragma unroll
    for (int mf = 0; mf < 4; ++mf)
        #pragma unroll
        for (int nf = 0; nf < 2; ++nf)
            #pragma unroll
            for (int r = 0; r < 4; ++r)
                C[(size_t)(bm + wm*64 + mf*16 + lg*4 + r) * N + bn + wn*32 + nf*16 + lm]
                    = acc[mf][nf][r];
    #undef G_ISSUE
}

// ------- fused qkv prep: l2norm+split Q,K  and  transposed/permuted V ----
__global__ __launch_bounds__(256) void qkv_prep_kernel(
    const float* __restrict__ qkv,
    ushort_t* __restrict__ Qh, ushort_t* __restrict__ Ql,
    ushort_t* __restrict__ Kh, ushort_t* __restrict__ Kl,
    ushort_t* __restrict__ Vth, ushort_t* __restrict__ Vtl)
{
    __shared__ float Vf[64][65];
    const int id = blockIdx.x;
    const int bh = id >> 5, nt = id & 31;
    const int b = bh >> 3, h = bh & 7;
    const int n0 = nt * 64;
    const int tid = threadIdx.x;
    {
        const int row = tid >> 2, dseg = tid & 3;
        const float* src = qkv + ((size_t)(b * NSEQ + n0 + row)) * QKV3
                         + h * 192 + dseg * 48;
        float f[48];
        #pragma unroll
        for (int i = 0; i < 12; ++i)
            *(float4*)&f[i*4] = *(const float4*)(src + i*4);
        float nq = 0.f, nk = 0.f;
        #pragma unroll
        for (int e = 0; e < 16; ++e) {
            nq = fmaf(f[3*e], f[3*e], nq);
            nk = fmaf(f[3*e+1], f[3*e+1], nk);
        }
        nq += __shfl_xor(nq, 1); nq += __shfl_xor(nq, 2);
        nk += __shfl_xor(nk, 1); nk += __shfl_xor(nk, 2);
        float rq = 1.f / fmaxf(sqrtf(nq), 1e-12f);
        float rk = 1.f / fmaxf(sqrtf(nk), 1e-12f);
        short8 qh8[2], ql8[2], kh8[2], kl8[2];
        #pragma unroll
        for (int e = 0; e < 16; ++e) {
            float q = f[3*e] * rq, k = f[3*e+1] * rk;
            unsigned short qhi = f2bf(q), khi = f2bf(k);
            qh8[e>>3][e&7] = (short)qhi;
            ql8[e>>3][e&7] = (short)f2bf(q - bf2f(qhi));
            kh8[e>>3][e&7] = (short)khi;
            kl8[e>>3][e&7] = (short)f2bf(k - bf2f(khi));
            Vf[dseg*16 + e][row] = f[3*e+2];
        }
        size_t o = ((size_t)bh * NSEQ + n0 + row) * DIM + dseg * 16;
        *(short8*)(Qh + o) = qh8[0]; *(short8*)(Qh + o + 8) = qh8[1];
        *(short8*)(Ql + o) = ql8[0]; *(short8*)(Ql + o + 8) = ql8[1];
        *(short8*)(Kh + o) = kh8[0]; *(short8*)(Kh + o + 8) = kh8[1];
        *(short8*)(Kl + o) = kl8[0]; *(short8*)(Kl + o + 8) = kl8[1];
    }
    __syncthreads();
    {   // Vt[bh][d][n] with the PV fragment j-permutation (within 32-blocks)
        const int d = tid >> 2, seg = tid & 3;
        ushort_t th[16], tl[16];
        #pragma unroll
        for (int t = 0; t < 16; ++t) {
            int p = seg * 16 + t;
            int s = (p & 35) | ((p & 4) << 2) | ((p >> 1) & 12);
            float v = Vf[d][s];
            unsigned short hi = f2bf(v);
            th[t] = hi;
            tl[t] = f2bf(v - bf2f(hi));
        }
        size_t o = ((size_t)bh * DIM + d) * NSEQ + n0 + seg * 16;
        *(uint4*)(Vth + o)     = *(uint4*)&th[0];
        *(uint4*)(Vth + o + 8) = *(uint4*)&th[8];
        *(uint4*)(Vtl + o)     = *(uint4*)&tl[0];
        *(uint4*)(Vtl + o + 8) = *(uint4*)&tl[8];
    }
}

// ---------------- MFMA flash attention v7b: runtime j-split --------------
// Q-tile 128 (4 waves x 32 rows), KVBLK=32 dbuf, grid 256*ns
// launch_bounds (256,3): natural 84-VGPR allocation (NO spill); at 84<=128
// VGPR the HW still co-schedules 4 blocks/CU when LDS permits (147KB<160KB).
__global__ __launch_bounds__(256, 3) void attn_mfma_kernel(
    const ushort_t* __restrict__ Qh, const ushort_t* __restrict__ Ql,
    const ushort_t* __restrict__ Kh, const ushort_t* __restrict__ Kl,
    const ushort_t* __restrict__ Vth, const ushort_t* __restrict__ Vtl,
    const float* __restrict__ bias, const float* __restrict__ temp_p,
    const uint8_t* __restrict__ mask,
    float* __restrict__ Opart, float* __restrict__ Ml,
    int ns, int base, int rem)
{
    __shared__ ushort_t KsH[2][32][72], KsL[2][32][72];   // [buf][j][d]
    __shared__ ushort_t VsH[2][64][36], VsL[2][64][36];   // [buf][d][j-perm]

    const int id = blockIdx.x;
    const int h = id & 7;                  // XCD-grouped
    const int rest = id >> 3;              // 0 .. 2*16*ns-1
    const int per_b = 16 * ns;
    const int b = rest / per_b;
    const int r2 = rest - b * per_b;
    const int js = r2 >> 4;                // 0..ns-1
    const int qt = r2 & 15;
    const int bh = b * 8 + h;
    const int i0 = qt * 128;
    const int tid = threadIdx.x;
    const int wave = tid >> 6, lane = tid & 63;
    const int lg = lane >> 4, lm = lane & 15;
    const int qbase = i0 + wave * 32;
    const float temp = *temp_p;
    const int krow = tid >> 3, kseg = tid & 7;   // K staging: 32 x 8
    const int vrow = tid >> 2, vseg = tid & 3;   // V staging: 64 x 4

    short8 qfh[2][2], qfl[2][2];
    #pragma unroll
    for (int m = 0; m < 2; ++m) {
        size_t qo = ((size_t)(bh * NSEQ + qbase + 16*m + lm)) * DIM + lg * 8;
        qfh[m][0] = *(const short8*)(Qh + qo);
        qfh[m][1] = *(const short8*)(Qh + qo + 32);
        qfl[m][0] = *(const short8*)(Ql + qo);
        qfl[m][1] = *(const short8*)(Ql + qo + 32);
    }
    bool rowm[2];
    rowm[0] = mask[(size_t)b * NSEQ + qbase + lm] != 0;
    rowm[1] = mask[(size_t)b * NSEQ + qbase + 16 + lm] != 0;

    float m_r[2] = {-FLT_MAX, -FLT_MAX};
    float l_r[2] = {0.f, 0.f};
    f32x4 oa[2][4];
    #pragma unroll
    for (int m = 0; m < 2; ++m)
        #pragma unroll
        for (int dt = 0; dt < 4; ++dt) oa[m][dt] = (f32x4){0.f,0.f,0.f,0.f};

    const int NT = base + (js < rem ? 1 : 0);
    const int tstart = js * base + (js < rem ? js : rem);
    const int jbase = tstart * 32;
    uint4 skh, skl, svh, svl;

    #define A_ISSUE(J0) {                                                      \
        size_t gk = ((size_t)(bh * NSEQ) + (J0) + krow) * DIM + kseg*8;        \
        size_t gv = ((size_t)(bh * DIM) + vrow) * NSEQ + (J0) + vseg*8;        \
        skh = *(const uint4*)(Kh  + gk);                                       \
        skl = *(const uint4*)(Kl  + gk);                                       \
        svh = *(const uint4*)(Vth + gv);                                       \
        svl = *(const uint4*)(Vtl + gv); }
    #define STAGE(BUF) {                                                       \
        *(uint4*)&KsH[BUF][krow][kseg*8] = skh;                                \
        *(uint4*)&KsL[BUF][krow][kseg*8] = skl;                                \
        *(uint4*)&VsH[BUF][vrow][vseg*8] = svh;                                \
        *(uint4*)&VsL[BUF][vrow][vseg*8] = svl; }

    A_ISSUE(jbase)
    STAGE(0)
    A_ISSUE(jbase + 32)
    float4 bb[2][2];
    #pragma unroll
    for (int m = 0; m < 2; ++m)
        #pragma unroll
        for (int jt = 0; jt < 2; ++jt)
            bb[m][jt] = *(const float4*)(bias
                + ((size_t)h * NSEQ + qbase + 16*m + lm) * NSEQ
                + jbase + jt*16 + lg*4);
    uint8_t mk = mask[(size_t)b * NSEQ + jbase + (lane & 31)];
    __syncthreads();

    #pragma unroll 2
    for (int t = 0; t < NT; ++t) {
        const int cur = t & 1;
        const int j0 = jbase + t * 32;

        // ---- prefetch next tile's bias/mask; stage t+1; issue t+2 ----
        float4 bbn[2][2];
        uint8_t mkn = 0;
        if (t + 1 < NT) {
            #pragma unroll
            for (int m = 0; m < 2; ++m)
                #pragma unroll
                for (int jt = 0; jt < 2; ++jt)
                    bbn[m][jt] = *(const float4*)(bias
                        + ((size_t)h * NSEQ + qbase + 16*m + lm) * NSEQ
                        + j0 + 32 + jt*16 + lg*4);
            mkn = mask[(size_t)b * NSEQ + j0 + 32 + (lane & 31)];
            STAGE(cur ^ 1)
            if (t + 2 < NT) A_ISSUE(j0 + 64)
        }
        unsigned long long bal = __ballot(mk != 0);   // low 32 bits = tile cols

        // ---- S^T = K.Q (swapped), split MFMA ----
        f32x4 sac[2][2];
        #pragma unroll
        for (int m = 0; m < 2; ++m)
            #pragma unroll
            for (int jt = 0; jt < 2; ++jt) sac[m][jt] = (f32x4){0.f,0.f,0.f,0.f};
        __builtin_amdgcn_s_setprio(1);
        #pragma unroll
        for (int jt = 0; jt < 2; ++jt)
            #pragma unroll
            for (int ks = 0; ks < 2; ++ks) {
                short8 kbh = *(const short8*)(&KsH[cur][jt*16 + lm][ks*32 + lg*8]);
                short8 kbl = *(const short8*)(&KsL[cur][jt*16 + lm][ks*32 + lg*8]);
                #pragma unroll
                for (int m = 0; m < 2; ++m) {
                    sac[m][jt] = __builtin_amdgcn_mfma_f32_16x16x32_bf16(kbh, qfh[m][ks], sac[m][jt], 0, 0, 0);
                    sac[m][jt] = __builtin_amdgcn_mfma_f32_16x16x32_bf16(kbh, qfl[m][ks], sac[m][jt], 0, 0, 0);
                    sac[m][jt] = __builtin_amdgcn_mfma_f32_16x16x32_bf16(kbl, qfh[m][ks], sac[m][jt], 0, 0, 0);
                }
            }
        __builtin_amdgcn_s_setprio(0);

        // ---- in-register online softmax with defer-max ----
        short8 pah[2], pal[2];
        #pragma unroll
        for (int m = 0; m < 2; ++m) {
            float sv[2][4];
            #pragma unroll
            for (int jt = 0; jt < 2; ++jt) {
                unsigned int nib = (unsigned int)(bal >> (jt*16 + lg*4)) & 0xFu;
                #pragma unroll
                for (int r = 0; r < 4; ++r) {
                    bool dead = rowm[m] || ((nib >> r) & 1u);
                    float bv = (r == 0) ? bb[m][jt].x : (r == 1) ? bb[m][jt].y
                             : (r == 2) ? bb[m][jt].z : bb[m][jt].w;
                    sv[jt][r] = dead ? -FLT_MAX : fmaf(sac[m][jt][r], temp, bv);
                }
            }
            float pmax = fmaxf(fmaxf(fmaxf(sv[0][0], sv[0][1]), fmaxf(sv[0][2], sv[0][3])),
                               fmaxf(fmaxf(sv[1][0], sv[1][1]), fmaxf(sv[1][2], sv[1][3])));
            pmax = fmaxf(pmax, __shfl_xor(pmax, 16));
            pmax = fmaxf(pmax, __shfl_xor(pmax, 32));
            if (!__all(pmax <= m_r[m] + 8.f)) {      // rare rescale
                float mn = fmaxf(m_r[m], pmax);
                float sc = __expf(m_r[m] - mn);
                m_r[m] = mn;
                l_r[m] *= sc;
                #pragma unroll
                for (int r = 0; r < 4; ++r) {
                    float sq = __shfl(sc, lg*4 + r);
                    #pragma unroll
                    for (int dt = 0; dt < 4; ++dt) oa[m][dt][r] *= sq;
                }
            }
            float rs = 0.f;
            #pragma unroll
            for (int jt = 0; jt < 2; ++jt)
                #pragma unroll
                for (int r = 0; r < 4; ++r) {
                    float pf = __expf(sv[jt][r] - m_r[m]);
                    rs += pf;
                    unsigned short hi = f2bf(pf);
                    pah[m][jt*4 + r] = (short)hi;
                    pal[m][jt*4 + r] = (short)f2bf(pf - bf2f(hi));
                }
            rs += __shfl_xor(rs, 16);
            rs += __shfl_xor(rs, 32);
            l_r[m] += rs;
        }

        // ---- O += P.V ----
        __builtin_amdgcn_s_setprio(1);
        #pragma unroll
        for (int dt = 0; dt < 4; ++dt) {
            short8 vbh = *(const short8*)(&VsH[cur][dt*16 + lm][lg*8]);
            short8 vbl = *(const short8*)(&VsL[cur][dt*16 + lm][lg*8]);
            #pragma unroll
            for (int m = 0; m < 2; ++m) {
                oa[m][dt] = __builtin_amdgcn_mfma_f32_16x16x32_bf16(pah[m], vbh, oa[m][dt], 0, 0, 0);
                oa[m][dt] = __builtin_amdgcn_mfma_f32_16x16x32_bf16(pah[m], vbl, oa[m][dt], 0, 0, 0);
                oa[m][dt] = __builtin_amdgcn_mfma_f32_16x16x32_bf16(pal[m], vbh, oa[m][dt], 0, 0, 0);
            }
        }
        __builtin_amdgcn_s_setprio(0);
        __syncthreads();
        #pragma unroll
        for (int m = 0; m < 2; ++m)
            #pragma unroll
            for (int jt = 0; jt < 2; ++jt) bb[m][jt] = bbn[m][jt];
        mk = mkn;
    }
    #undef A_ISSUE
    #undef STAGE

    // ---- epilogue: f32 partials + (m,l) ----
    #pragma unroll
    for (int m = 0; m < 2; ++m)
        #pragma unroll
        for (int dt = 0; dt < 4; ++dt)
            #pragma unroll
            for (int r = 0; r < 4; ++r)
                Opart[((size_t)(js*16 + bh) * NSEQ + qbase + 16*m + lg*4 + r) * 64
                      + dt*16 + lm] = oa[m][dt][r];
    if (lane < 16) {
        #pragma unroll
        for (int m = 0; m < 2; ++m) {
            size_t mi = ((size_t)(js*16 + bh) * NSEQ + qbase + 16*m + lm) * 2;
            Ml[mi]     = m_r[m];
            Ml[mi + 1] = l_r[m];
        }
    }
}

// ------- merge ns j-split partials -> AO f32 [M][HD] ---------------------
__global__ __launch_bounds__(256) void merge_kernel(
    const float* __restrict__ Opart, const float* __restrict__ Ml,
    float* __restrict__ AO, int ns)
{
    int row = blockIdx.x * 4 + (threadIdx.x >> 6);
    int d = threadIdx.x & 63;
    int bh = row >> 11, n = row & (NSEQ - 1);
    int bq = bh >> 3, hq = bh & 7;
    float mv[4], lv[4];
    float mm = -FLT_MAX;
    for (int p = 0; p < ns; ++p) {
        size_t mi = ((size_t)(p*16 + bh) * NSEQ + n) * 2;
        mv[p] = Ml[mi]; lv[p] = Ml[mi + 1];
        mm = fmaxf(mm, mv[p]);
    }
    float l = 0.f, o = 0.f;
    for (int p = 0; p < ns; ++p) {
        float w = __expf(mv[p] - mm);
        l += lv[p] * w;
        o += Opart[((size_t)(p*16 + bh) * NSEQ + n) * 64 + d] * w;
    }
    o /= l;
    AO[((size_t)(bq * NSEQ + n)) * HD + hq * DIM + d] = o;
}

extern "C" void kernel_launch(void* const* d_in, const int* in_sizes, int n_in,
                              void* d_out, int out_size, void* d_ws, size_t ws_size,
                              hipStream_t stream)
{
    const float*   x        = (const float*)d_in[0];
    const float*   w_qkv    = (const float*)d_in[1];
    const float*   w_out    = (const float*)d_in[2];
    const float*   pos_bias = (const float*)d_in[3];
    const float*   temp     = (const float*)d_in[4];
    const uint8_t* mask     = (const uint8_t*)d_in[5];
    float* out = (float*)d_out;

    const int M = BATCH * NSEQ;                        // 4096
    const size_t NE = (size_t)BATCH * HEADS * NSEQ * DIM;
    const size_t QKVB   = (size_t)M * QKV3 * 4;        // qkv_lin bytes (25.2 MB)
    const size_t PART1  = (size_t)16 * NSEQ * 64 * 4;  // per-split partial bytes (8.4 MB)
    const size_t WB     = (size_t)(QKV3 + HD) * CIN * 2 * 2;  // weight h+l bytes
    const size_t REG2   = NE * 2 * 6;                  // Q/K/Vt h+l (25.2 MB)

    // choose j-split from available workspace (deterministic: ws_size fixed)
    int ns = 4;
    {
        size_t reg0 = QKVB > (size_t)ns * PART1 ? QKVB : (size_t)ns * PART1;
        size_t mlb  = (size_t)ns * 16 * NSEQ * 2 * 4;
        if (reg0 + WB + mlb + REG2 > ws_size) ns = 3;
    }
    const int base = 64 / ns, rem = 64 % ns;

    char* ws = (char*)d_ws;
    size_t reg0 = QKVB > (size_t)ns * PART1 ? QKVB : (size_t)ns * PART1;
    float* qkv_lin = (float*)ws;
    float* OpartP  = (float*)ws;                 // aliases qkv_lin (dead by then)
    size_t off = reg0;
    ushort_t* WqkvTh = (ushort_t*)(ws + off); off += (size_t)QKV3 * CIN * 2;
    ushort_t* WqkvTl = (ushort_t*)(ws + off); off += (size_t)QKV3 * CIN * 2;
    ushort_t* WoutTh = (ushort_t*)(ws + off); off += (size_t)HD * CIN * 2;
    ushort_t* WoutTl = (ushort_t*)(ws + off); off += (size_t)HD * CIN * 2;
    float*    MlP    = (float*)(ws + off);    off += (size_t)ns * 16 * NSEQ * 2 * 4;
    char* reg2 = ws + off;
    ushort_t* Qh  = (ushort_t*)reg2;
    ushort_t* Ql  = Qh + NE;
    ushort_t* Kh  = Ql + NE;
    ushort_t* Kl  = Kh + NE;
    ushort_t* Vth = Kl + NE;
    ushort_t* Vtl = Vth + NE;
    float* AO = (float*)reg2;       // 8 MB = Qh+Ql slots (dead after attn)

    // 1. both weight splits in one launch
    split_wT_kernel<<<dim3(32, CIN/64), 256, 0, stream>>>(
        w_qkv, w_out, WqkvTh, WqkvTl, WoutTh, WoutTl);
    // 2. qkv projection
    gemm_split_kernel<<<dim3(QKV3/64, M/128), 256, 0, stream>>>(
        x, WqkvTh, WqkvTl, qkv_lin, M, QKV3, CIN);
    // 3. fused l2norm/split + V transpose
    qkv_prep_kernel<<<dim3(BATCH * HEADS * (NSEQ/64)), 256, 0, stream>>>(
        qkv_lin, Qh, Ql, Kh, Kl, Vth, Vtl);
    // 4. attention (j-split ns; Opart overwrites qkv_lin)
    attn_mfma_kernel<<<dim3(256 * ns), 256, 0, stream>>>(
        Qh, Ql, Kh, Kl, Vth, Vtl, pos_bias, temp, mask, OpartP, MlP,
        ns, base, rem);
    // 5. merge partials -> AO f32 (overwrites Qh/Ql)
    merge_kernel<<<dim3(M * HEADS / 4), 256, 0, stream>>>(OpartP, MlP, AO, ns);
    // 6. out projection
    gemm_split_kernel<<<dim3(HD/64, M/128), 256, 0, stream>>>(
        AO, WoutTh, WoutTl, out, M, HD, CIN);
}